// Round 19
// baseline (27.299 us; speedup 1.0000x reference)
//
#include <hip/hip_runtime.h>
#include <hip/hip_bf16.h>

#define BB 4096   // batch
#define DD 64     // event dim
#define HH 512    // hidden

typedef short short8 __attribute__((ext_vector_type(8)));   // 8 bf16
typedef float f32x4  __attribute__((ext_vector_type(4)));
typedef __hip_bfloat16 bf16;

// branchless fast tanh: 1 - 2/(1+e^{2x}); exact limits at +-inf
__device__ __forceinline__ float tanh_fast(float x) {
    float e = __expf(2.0f * x);
    return 1.0f - __fdividef(2.0f, 1.0f + e);
}

// swizzled LDS store of 4 CONSECUTIVE cols (col % 4 == 0) as one b64 write
__device__ __forceinline__ void st_swz64(bf16* base, int row, int col, int rs,
                                         float a, float b, float c, float d) {
    ushort4 v;
    v.x = __bfloat16_as_ushort(__float2bfloat16(a));
    v.y = __bfloat16_as_ushort(__float2bfloat16(b));
    v.z = __bfloat16_as_ushort(__float2bfloat16(c));
    v.w = __bfloat16_as_ushort(__float2bfloat16(d));
    int e = row * rs + ((((col >> 3) ^ (row & 7))) << 3) + (col & 7);
    *(ushort4*)(base + e) = v;
}

// single 1KB fragment load (proven R10/R12)
#define GLD1(dst, addr)                                                      \
  asm volatile("global_load_dwordx4 %0, %1, off" : "=&v"(dst) : "v"(addr))

// 2KB entry = 2 x 1KB
#define GLD2(e0, e1, addr)                                                   \
  asm volatile("global_load_dwordx4 %0, %2, off\n\t"                         \
               "global_load_dwordx4 %1, %2, off offset:1024"                 \
               : "=&v"(e0), "=&v"(e1) : "v"(addr))

// 4KB entry = 4 x 1KB
#define GLD4(e0, e1, e2, e3, addr)                                           \
  asm volatile("global_load_dwordx4 %0, %4, off\n\t"                         \
               "global_load_dwordx4 %1, %4, off offset:1024\n\t"             \
               "global_load_dwordx4 %2, %4, off offset:2048\n\t"             \
               "global_load_dwordx4 %3, %4, off offset:3072"                 \
               : "=&v"(e0), "=&v"(e1), "=&v"(e2), "=&v"(e3) : "v"(addr))

// counted wait + compiler motion fence (rule 18)
#define WAITV(n)                                                             \
  do { asm volatile("s_waitcnt vmcnt(" #n ")" ::: "memory");                 \
       __builtin_amdgcn_sched_barrier(0); } while (0)

// LDS-only barrier: raw s_barrier with lgkmcnt drain but NO vmcnt drain
#define LGKMBAR()                                                            \
  do { asm volatile("s_waitcnt lgkmcnt(0)" ::: "memory");                    \
       __builtin_amdgcn_s_barrier();                                         \
       __builtin_amdgcn_sched_barrier(0); } while (0)

// ===========================================================================
// Packed weights (16-col x 32-k tiles, tile = 512 elems = 1KB; lane l:
// kq=l>>4, r=l&15 owns B[col=base+r][k=kbase+kq*8+j], j=0..7 = 16B).
// A-operand of swapped mfma(Wfrag, actfrag) -> D[wcol][batchrow].
//   W1p: T = w*4 + s*2 + f ; W2p/Pp: T = cw16*16 + s ; W3p: T = q*4 + f
// ===========================================================================
__global__ __launch_bounds__(256) void prep_kernel(
    const float* __restrict__ t, const float* __restrict__ W1,
    const float* __restrict__ b1, const float* __restrict__ W2,
    const float* __restrict__ W3, const float* __restrict__ b3,
    bf16* __restrict__ W1p, bf16* __restrict__ W2p, bf16* __restrict__ W3p,
    bf16* __restrict__ Pp, float* __restrict__ b1eff, float* __restrict__ out)
{
    const int tid  = threadIdx.x;
    const int bx   = blockIdx.x;
    const int lane = tid & 63;
    const int r    = lane & 15;
    const int kq   = lane >> 4;

    if (bx < 160) {
        int T = bx * 4 + (tid >> 6);     // 0..639
        const float* src;
        bf16* dst;
        int stride;
        if (T < 64) {            // W1p
            int w = T >> 2, s = (T >> 1) & 1, f = T & 1;
            src = W1 + (size_t)(s * 32 + kq * 8) * HH + (w * 2 + f) * 16 + r;
            stride = HH;
            dst = W1p + (size_t)T * 512 + lane * 8;
        } else if (T < 576) {    // W2p
            int tt = T - 64;
            int cw = tt >> 4, s = tt & 15;
            src = W2 + (size_t)(s * 32 + kq * 8) * HH + cw * 16 + r;
            stride = HH;
            dst = W2p + (size_t)tt * 512 + lane * 8;
        } else {                 // W3p
            int tt = T - 576;
            int q = tt >> 2, f = tt & 3;
            src = W3 + (size_t)(q * 32 + kq * 8) * DD + f * 16 + r;
            stride = DD;
            dst = W3p + (size_t)tt * 512 + lane * 8;
        }
        short8 v;
#pragma unroll
        for (int j = 0; j < 8; ++j)
            v[j] = (short)__bfloat16_as_ushort(__float2bfloat16(src[(size_t)j * stride]));
        *(short8*)dst = v;
    } else if (bx < 672) {
        // Pp tile pt (one per block): out-col k = cw*16+r, reduce j = s*32+kq*8+jj
        __shared__ float part[4][64][8];
        int pt = bx - 160;                       // 0..511
        int cw = pt >> 4, s = pt & 15;
        int k  = cw * 16 + r;
        int j0 = s * 32 + kq * 8;
        int wq = tid >> 6;
        float acc[8] = {};
        const float* w3row = W3 + (size_t)k * DD + wq * 16;
        const float* w1base = W1 + (size_t)(wq * 16) * HH + j0;
#pragma unroll
        for (int d = 0; d < 16; ++d) {
            float w3 = w3row[d];
            const float4* w1p4 = (const float4*)(w1base + (size_t)d * HH);
            float4 x = w1p4[0], y = w1p4[1];
            acc[0] += x.x * w3; acc[1] += x.y * w3;
            acc[2] += x.z * w3; acc[3] += x.w * w3;
            acc[4] += y.x * w3; acc[5] += y.y * w3;
            acc[6] += y.z * w3; acc[7] += y.w * w3;
        }
        *(f32x4*)&part[wq][lane][0] = *(f32x4*)&acc[0];
        *(f32x4*)&part[wq][lane][4] = *(f32x4*)&acc[4];
        __syncthreads();
        if (wq == 0) {
            short8 v;
#pragma unroll
            for (int j = 0; j < 8; ++j) {
                float ssum = part[0][lane][j] + part[1][lane][j] +
                             part[2][lane][j] + part[3][lane][j];
                v[j] = (short)__bfloat16_as_ushort(
                    __float2bfloat16(ssum * W2[(size_t)(j0 + j) * HH + k]));
            }
            *(short8*)(Pp + (size_t)pt * 512 + lane * 8) = v;
        }
    } else if (bx == 672) {
        float tv = t[0];
        b1eff[tid]       = b1[tid]       + tv * W1[(size_t)64 * HH + tid];
        b1eff[tid + 256] = b1[tid + 256] + tv * W1[(size_t)64 * HH + tid + 256];
    } else {
        int idx = (bx - 673) * 1024 + tid * 4;   // 260 blocks, exact cover
        if (idx < BB * DD) {
            int col = idx & 63;
            *(float4*)(out + idx) =
                make_float4(b3[col], b3[col + 1], b3[col + 2], b3[col + 3]);
        } else {
            *(float4*)(out + idx) = make_float4(0.f, 0.f, 0.f, 0.f);
        }
    }
}

// ---------------------------------------------------------------------------
// fused_rows: 256 blocks x 1024 threads; bid = rt*4 + ch. Block = 64 batch
// rows x column-QUARTER (128 cols) -> 4x weight reuse per GLD (the R18-
// diagnosed binding resource). 16 waves: stream=wid>>3 (0:W2/h1, 1:Pp/at);
// each stream wave = 32 cols x 32 rows: per step 2 ds_read + 2 GLD1 + 4
// MFMA, ring 3-ahead vmcnt(6/4/2/0). bsq handoff via f32 LDS (overlays
// dead tail of `at`). L3 split-K over the quarter. v/trace: atomicAdd.
// LDS 157,696 B -> 1 block/CU.
// ---------------------------------------------------------------------------
__global__ __launch_bounds__(1024, 2) void fused_rows(
    const float* __restrict__ z, const bf16* __restrict__ W1p,
    const bf16* __restrict__ W2p, const bf16* __restrict__ W3p,
    const bf16* __restrict__ Pp, const float* __restrict__ b1eff,
    const float* __restrict__ b2,
    float* __restrict__ outV, float* __restrict__ outTr)
{
    __shared__ alignas(16) char smem[157696];
    bf16* zt   = (bf16*)smem;                  // [64][64]  swizzled  (8 KB)
    bf16* h1   = (bf16*)(smem + 8192);         // [64][512] swizzled  (64 KB)
    bf16* at   = (bf16*)(smem + 73728);        // [64][512] swizzled  (64 KB)
    float* bsqL = (float*)(smem + 105472);     // [64][132] f32, overlays at tail
    bf16* h2   = (bf16*)(smem + 139264);       // [64][128] swizzled  (16 KB)
    float* trp = (float*)(smem + 155648);      // [4][64] f32         (1 KB)
    float* vp  = (float*)(smem + 8192);        // [4][64][68] f32, overlays h1

    const int tid  = threadIdx.x;
    const int wid  = tid >> 6;                 // 0..15
    const int lane = tid & 63;
    const int r    = lane & 15;
    const int kq   = lane >> 4;
    const int rx   = r & 7;
    const int laneE = lane * 8;
    const int rt   = blockIdx.x >> 2;
    const int ch   = blockIdx.x & 3;           // column quarter
    const int bm   = rt * 64;
    const int stream = wid >> 3;               // 0: W2/h1, 1: Pp/at
    const int w8   = wid & 7;
    const int sw2  = w8 & 3;                   // 32-col strip in quarter
    const int rh   = w8 >> 2;                  // 32-row half

    // ---- preload biases BEFORE asm loads; pin live ----
    float4 b1v0 = *(const float4*)(b1eff + wid * 32 + kq * 4);
    float4 b1v1 = *(const float4*)(b1eff + wid * 32 + 16 + kq * 4);
    float4 b2v0 = *(const float4*)(b2 + ch * 128 + sw2 * 32 + kq * 4);
    float4 b2v1 = *(const float4*)(b2 + ch * 128 + sw2 * 32 + 16 + kq * 4);
    asm volatile("" :: "v"(b1v0.x), "v"(b1v0.y), "v"(b1v0.z), "v"(b1v0.w),
                       "v"(b1v1.x), "v"(b1v1.y), "v"(b1v1.z), "v"(b1v1.w),
                       "v"(b2v0.x), "v"(b2v0.y), "v"(b2v0.z), "v"(b2v0.w),
                       "v"(b2v1.x), "v"(b2v1.y), "v"(b2v1.z), "v"(b2v1.w));
    float b1a[2][4] = {{b1v0.x, b1v0.y, b1v0.z, b1v0.w},
                       {b1v1.x, b1v1.y, b1v1.z, b1v1.w}};
    float b2a[2][4] = {{b2v0.x, b2v0.y, b2v0.z, b2v0.w},
                       {b2v1.x, b2v1.y, b2v1.z, b2v1.w}};

    // ---- stage z: 64x64 f32 -> bf16 swizzled (float4 -> b64 store) ----
    {
        int i = tid * 4;
        int row = i >> 6, col = i & 63;
        float4 v = *(const float4*)(z + (size_t)(bm + row) * DD + col);
        st_swz64(zt, row, col, 64, v.x, v.y, v.z, v.w);
    }

    // ---- L1 prefetch: wave strip = 32 cols, 2 k-entries ----
    short8 q0, q1, q2, q3, p0, p1;
    const bf16* Wb1 = W1p + (size_t)wid * 2048 + laneE;
    GLD2(q0, q1, Wb1);
    GLD2(p0, p1, Wb1 + 1024);
    LGKMBAR();    // zt visible; weight loads stay in flight

    // ---- L1 (swapped): 64 rows x 32 cols per wave ----
    f32x4 acc1[4][2] = {};    // [g=rowgroup][f=colfrag]
    WAITV(2);
#pragma unroll
    for (int g = 0; g < 4; ++g) {
        short8 av = *(const short8*)(zt + (g * 16 + r) * 64 + ((kq ^ rx) << 3));
        acc1[g][0] = __builtin_amdgcn_mfma_f32_16x16x32_bf16(q0, av, acc1[g][0], 0, 0, 0);
        acc1[g][1] = __builtin_amdgcn_mfma_f32_16x16x32_bf16(q1, av, acc1[g][1], 0, 0, 0);
    }
    WAITV(0);
#pragma unroll
    for (int g = 0; g < 4; ++g) {
        short8 av = *(const short8*)(zt + (g * 16 + r) * 64 + (((4 + kq) ^ rx) << 3));
        acc1[g][0] = __builtin_amdgcn_mfma_f32_16x16x32_bf16(p0, av, acc1[g][0], 0, 0, 0);
        acc1[g][1] = __builtin_amdgcn_mfma_f32_16x16x32_bf16(p1, av, acc1[g][1], 0, 0, 0);
    }
    // stream-loop ring prologue: 3 steps x 2 frags in flight
    short8 rbA[4], rbB[4];
    const bf16* Wstr = (stream ? Pp : W2p)
                     + (size_t)(ch * 8 + sw2 * 2) * 8192 + laneE;   // frag f=0
    GLD1(rbA[0], Wstr);        GLD1(rbB[0], Wstr + 8192);
    GLD1(rbA[1], Wstr + 512);  GLD1(rbB[1], Wstr + 8704);
    GLD1(rbA[2], Wstr + 1024); GLD1(rbB[2], Wstr + 9216);
    // L1 epilogue: packed b64 stores
#pragma unroll
    for (int g = 0; g < 4; ++g)
#pragma unroll
        for (int f = 0; f < 2; ++f) {
            float hv[4], avv[4];
#pragma unroll
            for (int v = 0; v < 4; ++v) {
                hv[v]  = tanh_fast(acc1[g][f][v] + b1a[f][v]);
                avv[v] = fmaf(-hv[v], hv[v], 1.0f);
            }
            int rowq = g * 16 + r;
            int colq = wid * 32 + f * 16 + kq * 4;
            st_swz64(h1, rowq, colq, 512, hv[0], hv[1], hv[2], hv[3]);
            st_swz64(at, rowq, colq, 512, avv[0], avv[1], avv[2], avv[3]);
        }
    LGKMBAR();    // h1/at visible; ring loads stay in flight

    // ---- stream loop: 32 cols (2 frags) x 32 rows (2 rowgroups) ----
    const bf16* Ab = stream ? at : h1;
    const int arow0 = rh * 32 + r;
    f32x4 acc[2][2] = {};    // [g][f]
#pragma unroll
    for (int s = 0; s < 16; ++s) {
        int co = (((s * 4 + kq) ^ rx) << 3);
        short8 a0 = *(const short8*)(Ab + arow0 * 512 + co);
        short8 a1 = *(const short8*)(Ab + (arow0 + 16) * 512 + co);
        if (s + 3 < 16) {
            GLD1(rbA[(s + 3) & 3], Wstr + (s + 3) * 512);
            GLD1(rbB[(s + 3) & 3], Wstr + 8192 + (s + 3) * 512);
            WAITV(6);
        } else if (s + 2 < 16) { WAITV(4); }
        else if (s + 1 < 16)   { WAITV(2); }
        else                   { WAITV(0); }
        acc[0][0] = __builtin_amdgcn_mfma_f32_16x16x32_bf16(rbA[s & 3], a0, acc[0][0], 0, 0, 0);
        acc[0][1] = __builtin_amdgcn_mfma_f32_16x16x32_bf16(rbB[s & 3], a0, acc[0][1], 0, 0, 0);
        acc[1][0] = __builtin_amdgcn_mfma_f32_16x16x32_bf16(rbA[s & 3], a1, acc[1][0], 0, 0, 0);
        acc[1][1] = __builtin_amdgcn_mfma_f32_16x16x32_bf16(rbB[s & 3], a1, acc[1][1], 0, 0, 0);
    }
    // L3 prefetch for ALL waves (survives barriers)
    {
        const int kw = wid & 3;
        const bf16* Wb3 = W3p + (size_t)(ch * 4 + kw) * 2048 + laneE;
        GLD4(q0, q1, q2, q3, Wb3);
    }
    LGKMBAR();    // all loop reads of h1/at complete (at tail reusable)

    // ---- W2-waves: h2 + bsq (f32 LDS handoff) ----
    if (stream == 0) {
#pragma unroll
        for (int g = 0; g < 2; ++g) {
            int rowq = rh * 32 + g * 16 + r;
#pragma unroll
            for (int f = 0; f < 2; ++f) {
                float hv[4];
                f32x4 bq;
#pragma unroll
                for (int v = 0; v < 4; ++v) {
                    hv[v] = tanh_fast(acc[g][f][v] + b2a[f][v]);
                    bq[v] = fmaf(-hv[v], hv[v], 1.0f);
                }
                int colq = sw2 * 32 + f * 16 + kq * 4;
                st_swz64(h2, rowq, colq, 128, hv[0], hv[1], hv[2], hv[3]);
                *(f32x4*)(bsqL + rowq * 132 + colq) = bq;
            }
        }
    }
    LGKMBAR();    // h2 + bsqL visible

    // ---- E-waves: trace partials ----
    if (stream == 1) {
#pragma unroll
        for (int g = 0; g < 2; ++g) {
            int rowq = rh * 32 + g * 16 + r;
            f32x4 bq0 = *(const f32x4*)(bsqL + rowq * 132 + sw2 * 32 + kq * 4);
            f32x4 bq1 = *(const f32x4*)(bsqL + rowq * 132 + sw2 * 32 + 16 + kq * 4);
            float p = acc[g][0][0] * bq0[0] + acc[g][0][1] * bq0[1]
                    + acc[g][0][2] * bq0[2] + acc[g][0][3] * bq0[3]
                    + acc[g][1][0] * bq1[0] + acc[g][1][1] * bq1[1]
                    + acc[g][1][2] * bq1[2] + acc[g][1][3] * bq1[3];
            p += __shfl_xor(p, 16);
            p += __shfl_xor(p, 32);
            if (lane < 16) trp[sw2 * 64 + rh * 32 + g * 16 + lane] = p;
        }
    }

    // ---- L3 (all waves): v-partial = W3frag x h2frag over quarter K ----
    {
        const int kw = wid & 3, rp = wid >> 2;
        f32x4 c0 = {}, c1 = {}, c2 = {}, c3 = {};
        short8 av = *(const short8*)(h2 + (rp * 16 + r) * 128 + (((kw * 4 + kq) ^ rx) << 3));
        WAITV(0);
        c0 = __builtin_amdgcn_mfma_f32_16x16x32_bf16(q0, av, c0, 0, 0, 0);
        c1 = __builtin_amdgcn_mfma_f32_16x16x32_bf16(q1, av, c1, 0, 0, 0);
        c2 = __builtin_amdgcn_mfma_f32_16x16x32_bf16(q2, av, c2, 0, 0, 0);
        c3 = __builtin_amdgcn_mfma_f32_16x16x32_bf16(q3, av, c3, 0, 0, 0);
        int base = kw * 4352 + (rp * 16 + r) * 68 + kq * 4;
        *(f32x4*)(vp + base)      = c0;
        *(f32x4*)(vp + base + 16) = c1;
        *(f32x4*)(vp + base + 32) = c2;
        *(f32x4*)(vp + base + 48) = c3;
    }
    LGKMBAR();

    // ---- final: reduce partials; atomicAdd v and trace ----
#pragma unroll
    for (int it = 0; it < 4; ++it) {
        int i = it * 1024 + tid;
        int row = i >> 6, col = i & 63;
        float s = vp[row * 68 + col]        + vp[4352 + row * 68 + col]
                + vp[8704 + row * 68 + col] + vp[13056 + row * 68 + col];
        atomicAdd(outV + (size_t)(bm + row) * DD + col, s);
    }
    if (tid < 64) {
        float s = trp[tid] + trp[64 + tid] + trp[128 + tid] + trp[192 + tid];
        atomicAdd(outTr + bm + tid, -s);
    }
}

extern "C" void kernel_launch(void* const* d_in, const int* in_sizes, int n_in,
                              void* d_out, int out_size, void* d_ws, size_t ws_size,
                              hipStream_t stream)
{
    const float* z  = (const float*)d_in[0];
    const float* t  = (const float*)d_in[2];
    const float* W1 = (const float*)d_in[3];
    const float* b1 = (const float*)d_in[4];
    const float* W2 = (const float*)d_in[5];
    const float* b2 = (const float*)d_in[6];
    const float* W3 = (const float*)d_in[7];
    const float* b3 = (const float*)d_in[8];
    float* out = (float*)d_out;                 // v [4096*64] then dlogp [4096]
    float* out_tr = out + (size_t)BB * DD;

    char* w = (char*)d_ws;
    auto alloc = [&](size_t bytes) {
        char* p = w;
        w += (bytes + 255) & ~(size_t)255;
        return p;
    };
    bf16* W1p   = (bf16*)alloc((size_t)64  * 512 * 2);
    bf16* W2p   = (bf16*)alloc((size_t)512 * 512 * 2);
    bf16* W3p   = (bf16*)alloc((size_t)64  * 512 * 2);
    bf16* Pp    = (bf16*)alloc((size_t)512 * 512 * 2);
    float* b1eff = (float*)alloc((size_t)HH * 4);

    // prep: packs + P (512-block parallel) + b1eff + output init
    prep_kernel<<<933, 256, 0, stream>>>(t, W1, b1, W2, W3, b3,
                                         W1p, W2p, W3p, Pp, b1eff, out);
    fused_rows<<<64 * 4, 1024, 0, stream>>>(z, W1p, W2p, W3p, Pp,
                                            b1eff, b2, out, out_tr);
}

// Round 20
// 22.556 us; speedup vs baseline: 1.2103x; 1.2103x over previous
//
#include <hip/hip_runtime.h>
#include <hip/hip_bf16.h>

#define BB 4096   // batch
#define DD 64     // event dim
#define HH 512    // hidden

typedef short short8 __attribute__((ext_vector_type(8)));   // 8 bf16
typedef float f32x4  __attribute__((ext_vector_type(4)));
typedef __hip_bfloat16 bf16;

// branchless fast tanh: 1 - 2/(1+e^{2x}); exact limits at +-inf
__device__ __forceinline__ float tanh_fast(float x) {
    float e = __expf(2.0f * x);
    return 1.0f - __fdividef(2.0f, 1.0f + e);
}

// swizzled LDS store of 4 CONSECUTIVE cols (col % 4 == 0) as one b64 write
__device__ __forceinline__ void st_swz64(bf16* base, int row, int col, int rs,
                                         float a, float b, float c, float d) {
    ushort4 v;
    v.x = __bfloat16_as_ushort(__float2bfloat16(a));
    v.y = __bfloat16_as_ushort(__float2bfloat16(b));
    v.z = __bfloat16_as_ushort(__float2bfloat16(c));
    v.w = __bfloat16_as_ushort(__float2bfloat16(d));
    int e = row * rs + ((((col >> 3) ^ (row & 7))) << 3) + (col & 7);
    *(ushort4*)(base + e) = v;
}

// single 1KB fragment load (proven R10/R12)
#define GLD1(dst, addr)                                                      \
  asm volatile("global_load_dwordx4 %0, %1, off" : "=&v"(dst) : "v"(addr))

// 2KB entry = 2 x 1KB
#define GLD2(e0, e1, addr)                                                   \
  asm volatile("global_load_dwordx4 %0, %2, off\n\t"                         \
               "global_load_dwordx4 %1, %2, off offset:1024"                 \
               : "=&v"(e0), "=&v"(e1) : "v"(addr))

// 4KB entry = 4 x 1KB
#define GLD4(e0, e1, e2, e3, addr)                                           \
  asm volatile("global_load_dwordx4 %0, %4, off\n\t"                         \
               "global_load_dwordx4 %1, %4, off offset:1024\n\t"             \
               "global_load_dwordx4 %2, %4, off offset:2048\n\t"             \
               "global_load_dwordx4 %3, %4, off offset:3072"                 \
               : "=&v"(e0), "=&v"(e1), "=&v"(e2), "=&v"(e3) : "v"(addr))

// counted wait + compiler motion fence (rule 18)
#define WAITV(n)                                                             \
  do { asm volatile("s_waitcnt vmcnt(" #n ")" ::: "memory");                 \
       __builtin_amdgcn_sched_barrier(0); } while (0)

// LDS-only barrier: raw s_barrier with lgkmcnt drain but NO vmcnt drain
#define LGKMBAR()                                                            \
  do { asm volatile("s_waitcnt lgkmcnt(0)" ::: "memory");                    \
       __builtin_amdgcn_s_barrier();                                         \
       __builtin_amdgcn_sched_barrier(0); } while (0)

// ===========================================================================
// Packed weights (16-col x 32-k tiles, tile = 512 elems = 1KB; lane l:
// kq=l>>4, r=l&15 owns B[col=base+r][k=kbase+kq*8+j], j=0..7 = 16B).
// A-operand of swapped mfma(Wfrag, actfrag) -> D[wcol][batchrow].
//   W1p: T = w*4 + s*2 + f ; W2p/Pp: T = cw16*16 + s ; W3p: T = q*4 + f
//
// Grid (933 blocks x 256):
//   [0,160)    pack W1p/W2p/W3p (4 tiles/block)
//   [160,672)  Pp: ONE tile per block, 4 waves split d-reduction 4-ways
//   672        b1eff
//   [673,933)  output init (v = b3 broadcast, trace = 0)
// ===========================================================================
__global__ __launch_bounds__(256) void prep_kernel(
    const float* __restrict__ t, const float* __restrict__ W1,
    const float* __restrict__ b1, const float* __restrict__ W2,
    const float* __restrict__ W3, const float* __restrict__ b3,
    bf16* __restrict__ W1p, bf16* __restrict__ W2p, bf16* __restrict__ W3p,
    bf16* __restrict__ Pp, float* __restrict__ b1eff, float* __restrict__ out)
{
    const int tid  = threadIdx.x;
    const int bx   = blockIdx.x;
    const int lane = tid & 63;
    const int r    = lane & 15;
    const int kq   = lane >> 4;

    if (bx < 160) {
        int T = bx * 4 + (tid >> 6);     // 0..639
        const float* src;
        bf16* dst;
        int stride;
        if (T < 64) {            // W1p
            int w = T >> 2, s = (T >> 1) & 1, f = T & 1;
            src = W1 + (size_t)(s * 32 + kq * 8) * HH + (w * 2 + f) * 16 + r;
            stride = HH;
            dst = W1p + (size_t)T * 512 + lane * 8;
        } else if (T < 576) {    // W2p
            int tt = T - 64;
            int cw = tt >> 4, s = tt & 15;
            src = W2 + (size_t)(s * 32 + kq * 8) * HH + cw * 16 + r;
            stride = HH;
            dst = W2p + (size_t)tt * 512 + lane * 8;
        } else {                 // W3p
            int tt = T - 576;
            int q = tt >> 2, f = tt & 3;
            src = W3 + (size_t)(q * 32 + kq * 8) * DD + f * 16 + r;
            stride = DD;
            dst = W3p + (size_t)tt * 512 + lane * 8;
        }
        short8 v;
#pragma unroll
        for (int j = 0; j < 8; ++j)
            v[j] = (short)__bfloat16_as_ushort(__float2bfloat16(src[(size_t)j * stride]));
        *(short8*)dst = v;
    } else if (bx < 672) {
        // Pp tile pt (one per block): out-col k = cw*16+r, reduce j = s*32+kq*8+jj
        __shared__ float part[4][64][8];
        int pt = bx - 160;                       // 0..511
        int cw = pt >> 4, s = pt & 15;
        int k  = cw * 16 + r;
        int j0 = s * 32 + kq * 8;
        int wq = tid >> 6;
        float acc[8] = {};
        const float* w3row = W3 + (size_t)k * DD + wq * 16;
        const float* w1base = W1 + (size_t)(wq * 16) * HH + j0;
#pragma unroll
        for (int d = 0; d < 16; ++d) {
            float w3 = w3row[d];
            const float4* w1p4 = (const float4*)(w1base + (size_t)d * HH);
            float4 x = w1p4[0], y = w1p4[1];
            acc[0] += x.x * w3; acc[1] += x.y * w3;
            acc[2] += x.z * w3; acc[3] += x.w * w3;
            acc[4] += y.x * w3; acc[5] += y.y * w3;
            acc[6] += y.z * w3; acc[7] += y.w * w3;
        }
        *(f32x4*)&part[wq][lane][0] = *(f32x4*)&acc[0];
        *(f32x4*)&part[wq][lane][4] = *(f32x4*)&acc[4];
        __syncthreads();
        if (wq == 0) {
            short8 v;
#pragma unroll
            for (int j = 0; j < 8; ++j) {
                float ssum = part[0][lane][j] + part[1][lane][j] +
                             part[2][lane][j] + part[3][lane][j];
                v[j] = (short)__bfloat16_as_ushort(
                    __float2bfloat16(ssum * W2[(size_t)(j0 + j) * HH + k]));
            }
            *(short8*)(Pp + (size_t)pt * 512 + lane * 8) = v;
        }
    } else if (bx == 672) {
        float tv = t[0];
        b1eff[tid]       = b1[tid]       + tv * W1[(size_t)64 * HH + tid];
        b1eff[tid + 256] = b1[tid + 256] + tv * W1[(size_t)64 * HH + tid + 256];
    } else {
        int idx = (bx - 673) * 1024 + tid * 4;   // 260 blocks, exact cover
        if (idx < BB * DD) {
            int col = idx & 63;
            *(float4*)(out + idx) =
                make_float4(b3[col], b3[col + 1], b3[col + 2], b3[col + 3]);
        } else {
            *(float4*)(out + idx) = make_float4(0.f, 0.f, 0.f, 0.f);
        }
    }
}

// ---------------------------------------------------------------------------
// fused_rows: R17 structure (best, 22.47us) + XCD-PAIRED block mapping:
// xcd = bid&7, idx = bid>>3; ch = idx>>4; rt = xcd*16 + (idx&15).
// Both ch-halves of a given rt now land on the SAME XCD -> their atomicAdd
// RMWs to the same v/trace lines stay in one L2 (no cross-XCD ping-pong).
// Also: z staging packed to b64 (512 threads x 4 cols).
// ---------------------------------------------------------------------------
__global__ __launch_bounds__(1024, 2) void fused_rows(
    const float* __restrict__ z, const bf16* __restrict__ W1p,
    const bf16* __restrict__ W2p, const bf16* __restrict__ W3p,
    const bf16* __restrict__ Pp, const float* __restrict__ b1eff,
    const float* __restrict__ b2,
    float* __restrict__ outV, float* __restrict__ outTr)
{
    __shared__ alignas(16) char smem[88064];
    bf16* zt   = (bf16*)smem;                 // [32][64]  swizzled (4 KB)
    bf16* h1   = (bf16*)(smem + 4096);        // [32][512] swizzled (32 KB)
    bf16* at   = (bf16*)(smem + 36864);       // [32][512] swizzled (32 KB)
    bf16* h2   = (bf16*)(smem + 69632);       // [32][256] swizzled (16 KB)
    float* trp = (float*)(smem + 86016);      // [16][32]           (2 KB)
    float* vp  = (float*)smem;                // [8][32][68] pad, overlays zt+h1+at

    const int tid  = threadIdx.x;
    const int wid  = tid >> 6;                // 0..15
    const int lane = tid & 63;
    const int r    = lane & 15;
    const int kq   = lane >> 4;
    const int rx   = r & 7;
    const int laneE = lane * 8;
    // XCD-paired mapping: both ch of a given rt share an XCD (bid%8)
    const int xcd  = blockIdx.x & 7;
    const int idx  = blockIdx.x >> 3;         // 0..31
    const int ch   = idx >> 4;                // 0..1
    const int rt   = xcd * 16 + (idx & 15);   // 0..127
    const int bm   = rt * 32;

    // ---- preload biases (float4 per 4 consecutive cols) BEFORE asm loads ----
    float4 b1v0 = *(const float4*)(b1eff + wid * 32 + kq * 4);
    float4 b1v1 = *(const float4*)(b1eff + wid * 32 + 16 + kq * 4);
    float4 b2v  = *(const float4*)(b2 + ch * 256 + wid * 16 + kq * 4);
    asm volatile("" :: "v"(b1v0.x), "v"(b1v0.y), "v"(b1v0.z), "v"(b1v0.w),
                       "v"(b1v1.x), "v"(b1v1.y), "v"(b1v1.z), "v"(b1v1.w),
                       "v"(b2v.x), "v"(b2v.y), "v"(b2v.z), "v"(b2v.w));
    float b1a[2][4] = {{b1v0.x, b1v0.y, b1v0.z, b1v0.w},
                       {b1v1.x, b1v1.y, b1v1.z, b1v1.w}};
    float b2a[4] = {b2v.x, b2v.y, b2v.z, b2v.w};

    // ---- stage z: 32x64 f32 -> bf16 swizzled, b64 packed (4 cols/thread) ----
    if (tid < 512) {
        int i = tid * 4;
        int row = i >> 6, col = i & 63;
        float4 v = *(const float4*)(z + (size_t)(bm + row) * DD + col);
        st_swz64(zt, row, col, 64, v.x, v.y, v.z, v.w);
    }

    // ---- L1 prefetch: wave strip = 32 cols, 2 entries (K=64) ----
    short8 q0, q1, q2, q3, p0, p1;
    const bf16* Wb1 = W1p + (size_t)wid * 2048 + laneE;
    GLD2(q0, q1, Wb1);
    GLD2(p0, p1, Wb1 + 1024);
    LGKMBAR();    // zt visible; L1 weight loads stay in flight

    // ---- L1 (swapped): acc1[g][f] = W1frag[f] x zfrag[g] ----
    f32x4 acc1[2][2] = {};    // [g=rowgroup][f=colfrag]
    WAITV(2);
#pragma unroll
    for (int g = 0; g < 2; ++g) {
        short8 av = *(const short8*)(zt + (g * 16 + r) * 64 + ((kq ^ rx) << 3));
        acc1[g][0] = __builtin_amdgcn_mfma_f32_16x16x32_bf16(q0, av, acc1[g][0], 0, 0, 0);
        acc1[g][1] = __builtin_amdgcn_mfma_f32_16x16x32_bf16(q1, av, acc1[g][1], 0, 0, 0);
    }
    WAITV(0);
#pragma unroll
    for (int g = 0; g < 2; ++g) {
        short8 av = *(const short8*)(zt + (g * 16 + r) * 64 + (((4 + kq) ^ rx) << 3));
        acc1[g][0] = __builtin_amdgcn_mfma_f32_16x16x32_bf16(p0, av, acc1[g][0], 0, 0, 0);
        acc1[g][1] = __builtin_amdgcn_mfma_f32_16x16x32_bf16(p1, av, acc1[g][1], 0, 0, 0);
    }
    // merged-loop prologue: 3 pairs (W2,Pp interleaved) = 6 loads in flight
    short8 rbW[4], rbP[4];
    const bf16* Wb2 = W2p + (size_t)(ch * 16 + wid) * 8192 + laneE;
    const bf16* WbE = Pp  + (size_t)(ch * 16 + wid) * 8192 + laneE;
    GLD1(rbW[0], Wb2);        GLD1(rbP[0], WbE);
    GLD1(rbW[1], Wb2 + 512);  GLD1(rbP[1], WbE + 512);
    GLD1(rbW[2], Wb2 + 1024); GLD1(rbP[2], WbE + 1024);
    // L1 epilogue: lane owns (row=g*16+r, cols wid*32+f*16+kq*4 ..+3) -> b64
#pragma unroll
    for (int g = 0; g < 2; ++g)
#pragma unroll
        for (int f = 0; f < 2; ++f) {
            float hv[4], avv[4];
#pragma unroll
            for (int v = 0; v < 4; ++v) {
                hv[v]  = tanh_fast(acc1[g][f][v] + b1a[f][v]);
                avv[v] = fmaf(-hv[v], hv[v], 1.0f);
            }
            int rowq = g * 16 + r;
            int colq = wid * 32 + f * 16 + kq * 4;
            st_swz64(h1, rowq, colq, 512, hv[0], hv[1], hv[2], hv[3]);
            st_swz64(at, rowq, colq, 512, avv[0], avv[1], avv[2], avv[3]);
        }
    LGKMBAR();    // h1/at visible; ring loads stay in flight

    // ---- merged L2 || E (swapped): one 16-step loop, 4 MFMA/step ----
    f32x4 acc2[2] = {};   // W2frag x h1frag -> [wcol][row]
    f32x4 accE[2] = {};   // Pfrag  x atfrag
#pragma unroll
    for (int s = 0; s < 16; ++s) {
        int co = (((s * 4 + kq) ^ rx) << 3);
        short8 a1v[2], aav[2];
#pragma unroll
        for (int g = 0; g < 2; ++g) {
            a1v[g] = *(const short8*)(h1 + (g * 16 + r) * 512 + co);
            aav[g] = *(const short8*)(at + (g * 16 + r) * 512 + co);
        }
        if (s + 3 < 16) {
            GLD1(rbW[(s + 3) & 3], Wb2 + (s + 3) * 512);
            GLD1(rbP[(s + 3) & 3], WbE + (s + 3) * 512);
            WAITV(6);
        } else if (s + 2 < 16) { WAITV(4); }
        else if (s + 1 < 16)   { WAITV(2); }
        else                   { WAITV(0); }
#pragma unroll
        for (int g = 0; g < 2; ++g) {
            acc2[g] = __builtin_amdgcn_mfma_f32_16x16x32_bf16(rbW[s & 3], a1v[g], acc2[g], 0, 0, 0);
            accE[g] = __builtin_amdgcn_mfma_f32_16x16x32_bf16(rbP[s & 3], aav[g], accE[g], 0, 0, 0);
        }
    }
    // epilogue: h2 (b64 packed) + bsq; L3 prefetch; trace (2-shfl reduce)
    f32x4 bsq[2];
    {
#pragma unroll
        for (int g = 0; g < 2; ++g) {
            float hv[4];
#pragma unroll
            for (int v = 0; v < 4; ++v) {
                hv[v] = tanh_fast(acc2[g][v] + b2a[v]);
                bsq[g][v] = fmaf(-hv[v], hv[v], 1.0f);
            }
            st_swz64(h2, g * 16 + r, wid * 16 + kq * 4, 256,
                     hv[0], hv[1], hv[2], hv[3]);
        }
        const int kw = wid & 7;
        const bf16* Wb3 = W3p + (size_t)(ch * 8 + kw) * 2048 + laneE;
        GLD4(q0, q1, q2, q3, Wb3);
#pragma unroll
        for (int g = 0; g < 2; ++g) {
            float p = accE[g][0] * bsq[g][0] + accE[g][1] * bsq[g][1]
                    + accE[g][2] * bsq[g][2] + accE[g][3] * bsq[g][3];
            p += __shfl_xor(p, 16);
            p += __shfl_xor(p, 32);
            if (lane < 16) trp[wid * 32 + g * 16 + lane] = p;
        }
    }
    LGKMBAR();    // h2/trp visible; h1/at reads done -> vp overlay safe

    // ---- L3 (swapped): v-partial = W3frag x h2frag; float4 vp stores ----
    {
        const int kw = wid & 7, rp = wid >> 3;
        f32x4 c0 = {}, c1 = {}, c2 = {}, c3 = {};
        short8 av = *(const short8*)(h2 + (rp * 16 + r) * 256 + (((kw * 4 + kq) ^ rx) << 3));
        WAITV(0);
        c0 = __builtin_amdgcn_mfma_f32_16x16x32_bf16(q0, av, c0, 0, 0, 0);
        c1 = __builtin_amdgcn_mfma_f32_16x16x32_bf16(q1, av, c1, 0, 0, 0);
        c2 = __builtin_amdgcn_mfma_f32_16x16x32_bf16(q2, av, c2, 0, 0, 0);
        c3 = __builtin_amdgcn_mfma_f32_16x16x32_bf16(q3, av, c3, 0, 0, 0);
        int base = kw * 2176 + (rp * 16 + r) * 68 + kq * 4;
        *(f32x4*)(vp + base)      = c0;
        *(f32x4*)(vp + base + 16) = c1;
        *(f32x4*)(vp + base + 32) = c2;
        *(f32x4*)(vp + base + 48) = c3;
    }
    LGKMBAR();

    // ---- final: reduce 8 k-chunk partials; atomicAdd v and trace ----
#pragma unroll
    for (int it = 0; it < 2; ++it) {
        int i = it * 1024 + tid;
        int row = i >> 6, col = i & 63;
        float s = 0.f;
#pragma unroll
        for (int kw = 0; kw < 8; ++kw) s += vp[kw * 2176 + row * 68 + col];
        atomicAdd(outV + (size_t)(bm + row) * DD + col, s);
    }
    if (tid < 32) {
        float s = 0.f;
#pragma unroll
        for (int w = 0; w < 16; ++w) s += trp[w * 32 + tid];
        atomicAdd(outTr + bm + tid, -s);
    }
}

extern "C" void kernel_launch(void* const* d_in, const int* in_sizes, int n_in,
                              void* d_out, int out_size, void* d_ws, size_t ws_size,
                              hipStream_t stream)
{
    const float* z  = (const float*)d_in[0];
    const float* t  = (const float*)d_in[2];
    const float* W1 = (const float*)d_in[3];
    const float* b1 = (const float*)d_in[4];
    const float* W2 = (const float*)d_in[5];
    const float* b2 = (const float*)d_in[6];
    const float* W3 = (const float*)d_in[7];
    const float* b3 = (const float*)d_in[8];
    float* out = (float*)d_out;                 // v [4096*64] then dlogp [4096]
    float* out_tr = out + (size_t)BB * DD;

    char* w = (char*)d_ws;
    auto alloc = [&](size_t bytes) {
        char* p = w;
        w += (bytes + 255) & ~(size_t)255;
        return p;
    };
    bf16* W1p   = (bf16*)alloc((size_t)64  * 512 * 2);
    bf16* W2p   = (bf16*)alloc((size_t)512 * 512 * 2);
    bf16* W3p   = (bf16*)alloc((size_t)64  * 512 * 2);
    bf16* Pp    = (bf16*)alloc((size_t)512 * 512 * 2);
    float* b1eff = (float*)alloc((size_t)HH * 4);

    // prep: packs + P (512-block parallel) + b1eff + output init
    prep_kernel<<<933, 256, 0, stream>>>(t, W1, b1, W2, W3, b3,
                                         W1p, W2p, W3p, Pp, b1eff, out);
    fused_rows<<<128 * 2, 1024, 0, stream>>>(z, W1p, W2p, W3p, Pp,
                                             b1eff, b2, out, out_tr);
}

// Round 21
// 22.349 us; speedup vs baseline: 1.2215x; 1.0093x over previous
//
#include <hip/hip_runtime.h>
#include <hip/hip_bf16.h>

#define BB 4096   // batch
#define DD 64     // event dim
#define HH 512    // hidden

typedef short short8 __attribute__((ext_vector_type(8)));   // 8 bf16
typedef float f32x4  __attribute__((ext_vector_type(4)));
typedef __hip_bfloat16 bf16;

// branchless fast tanh: 1 - 2/(1+e^{2x}); exact limits at +-inf
__device__ __forceinline__ float tanh_fast(float x) {
    float e = __expf(2.0f * x);
    return 1.0f - __fdividef(2.0f, 1.0f + e);
}

// swizzled LDS store of 4 CONSECUTIVE cols (col % 4 == 0) as one b64 write
__device__ __forceinline__ void st_swz64(bf16* base, int row, int col, int rs,
                                         float a, float b, float c, float d) {
    ushort4 v;
    v.x = __bfloat16_as_ushort(__float2bfloat16(a));
    v.y = __bfloat16_as_ushort(__float2bfloat16(b));
    v.z = __bfloat16_as_ushort(__float2bfloat16(c));
    v.w = __bfloat16_as_ushort(__float2bfloat16(d));
    int e = row * rs + ((((col >> 3) ^ (row & 7))) << 3) + (col & 7);
    *(ushort4*)(base + e) = v;
}

// single 1KB fragment load (proven R10/R12)
#define GLD1(dst, addr)                                                      \
  asm volatile("global_load_dwordx4 %0, %1, off" : "=&v"(dst) : "v"(addr))

// 2KB entry = 2 x 1KB
#define GLD2(e0, e1, addr)                                                   \
  asm volatile("global_load_dwordx4 %0, %2, off\n\t"                         \
               "global_load_dwordx4 %1, %2, off offset:1024"                 \
               : "=&v"(e0), "=&v"(e1) : "v"(addr))

// 4KB entry = 4 x 1KB
#define GLD4(e0, e1, e2, e3, addr)                                           \
  asm volatile("global_load_dwordx4 %0, %4, off\n\t"                         \
               "global_load_dwordx4 %1, %4, off offset:1024\n\t"             \
               "global_load_dwordx4 %2, %4, off offset:2048\n\t"             \
               "global_load_dwordx4 %3, %4, off offset:3072"                 \
               : "=&v"(e0), "=&v"(e1), "=&v"(e2), "=&v"(e3) : "v"(addr))

// counted wait + compiler motion fence (rule 18)
#define WAITV(n)                                                             \
  do { asm volatile("s_waitcnt vmcnt(" #n ")" ::: "memory");                 \
       __builtin_amdgcn_sched_barrier(0); } while (0)

// LDS-only barrier: raw s_barrier with lgkmcnt drain but NO vmcnt drain
#define LGKMBAR()                                                            \
  do { asm volatile("s_waitcnt lgkmcnt(0)" ::: "memory");                    \
       __builtin_amdgcn_s_barrier();                                         \
       __builtin_amdgcn_sched_barrier(0); } while (0)

// ===========================================================================
// Packed weights (16-col x 32-k tiles, tile = 512 elems = 1KB; lane l:
// kq=l>>4, r=l&15 owns B[col=base+r][k=kbase+kq*8+j], j=0..7 = 16B).
// A-operand of swapped mfma(Wfrag, actfrag) -> D[wcol][batchrow].
//   W1p: T = w*4 + s*2 + f ; W2p/Pp: T = cw16*16 + s ; W3p: T = q*4 + f
//
// Grid (933 blocks x 256):
//   [0,160)    pack W1p/W2p/W3p (4 tiles/block)
//   [160,672)  Pp: ONE tile per block, 4 waves split d-reduction 4-ways
//   672        b1eff
//   [673,933)  output init (v = b3 broadcast, trace = 0)
// ===========================================================================
__global__ __launch_bounds__(256) void prep_kernel(
    const float* __restrict__ t, const float* __restrict__ W1,
    const float* __restrict__ b1, const float* __restrict__ W2,
    const float* __restrict__ W3, const float* __restrict__ b3,
    bf16* __restrict__ W1p, bf16* __restrict__ W2p, bf16* __restrict__ W3p,
    bf16* __restrict__ Pp, float* __restrict__ b1eff, float* __restrict__ out)
{
    const int tid  = threadIdx.x;
    const int bx   = blockIdx.x;
    const int lane = tid & 63;
    const int r    = lane & 15;
    const int kq   = lane >> 4;

    if (bx < 160) {
        int T = bx * 4 + (tid >> 6);     // 0..639
        const float* src;
        bf16* dst;
        int stride;
        if (T < 64) {            // W1p
            int w = T >> 2, s = (T >> 1) & 1, f = T & 1;
            src = W1 + (size_t)(s * 32 + kq * 8) * HH + (w * 2 + f) * 16 + r;
            stride = HH;
            dst = W1p + (size_t)T * 512 + lane * 8;
        } else if (T < 576) {    // W2p
            int tt = T - 64;
            int cw = tt >> 4, s = tt & 15;
            src = W2 + (size_t)(s * 32 + kq * 8) * HH + cw * 16 + r;
            stride = HH;
            dst = W2p + (size_t)tt * 512 + lane * 8;
        } else {                 // W3p
            int tt = T - 576;
            int q = tt >> 2, f = tt & 3;
            src = W3 + (size_t)(q * 32 + kq * 8) * DD + f * 16 + r;
            stride = DD;
            dst = W3p + (size_t)tt * 512 + lane * 8;
        }
        short8 v;
#pragma unroll
        for (int j = 0; j < 8; ++j)
            v[j] = (short)__bfloat16_as_ushort(__float2bfloat16(src[(size_t)j * stride]));
        *(short8*)dst = v;
    } else if (bx < 672) {
        // Pp tile pt (one per block): out-col k = cw*16+r, reduce j = s*32+kq*8+jj
        __shared__ float part[4][64][8];
        int pt = bx - 160;                       // 0..511
        int cw = pt >> 4, s = pt & 15;
        int k  = cw * 16 + r;
        int j0 = s * 32 + kq * 8;
        int wq = tid >> 6;
        float acc[8] = {};
        const float* w3row = W3 + (size_t)k * DD + wq * 16;
        const float* w1base = W1 + (size_t)(wq * 16) * HH + j0;
#pragma unroll
        for (int d = 0; d < 16; ++d) {
            float w3 = w3row[d];
            const float4* w1p4 = (const float4*)(w1base + (size_t)d * HH);
            float4 x = w1p4[0], y = w1p4[1];
            acc[0] += x.x * w3; acc[1] += x.y * w3;
            acc[2] += x.z * w3; acc[3] += x.w * w3;
            acc[4] += y.x * w3; acc[5] += y.y * w3;
            acc[6] += y.z * w3; acc[7] += y.w * w3;
        }
        *(f32x4*)&part[wq][lane][0] = *(f32x4*)&acc[0];
        *(f32x4*)&part[wq][lane][4] = *(f32x4*)&acc[4];
        __syncthreads();
        if (wq == 0) {
            short8 v;
#pragma unroll
            for (int j = 0; j < 8; ++j) {
                float ssum = part[0][lane][j] + part[1][lane][j] +
                             part[2][lane][j] + part[3][lane][j];
                v[j] = (short)__bfloat16_as_ushort(
                    __float2bfloat16(ssum * W2[(size_t)(j0 + j) * HH + k]));
            }
            *(short8*)(Pp + (size_t)pt * 512 + lane * 8) = v;
        }
    } else if (bx == 672) {
        float tv = t[0];
        b1eff[tid]       = b1[tid]       + tv * W1[(size_t)64 * HH + tid];
        b1eff[tid + 256] = b1[tid + 256] + tv * W1[(size_t)64 * HH + tid + 256];
    } else {
        int idx = (bx - 673) * 1024 + tid * 4;   // 260 blocks, exact cover
        if (idx < BB * DD) {
            int col = idx & 63;
            *(float4*)(out + idx) =
                make_float4(b3[col], b3[col + 1], b3[col + 2], b3[col + 3]);
        } else {
            *(float4*)(out + idx) = make_float4(0.f, 0.f, 0.f, 0.f);
        }
    }
}

// ---------------------------------------------------------------------------
// fused_rows: R17 champion + STREAM-SPLIT merged loop. 16 waves:
// stream = wid>>3 (0: W2/h1, 1: Pp/at), sw = wid&7 -> cols sw*32..+32 of
// the ch-half (2 B-frags). Per step: 2 ds_read + 2 GLD1 + 4 MFMA (ds_reads
// HALVED vs R17, GLD/MFMA unchanged). E-waves recompute bsq from the bf16
// h2 tile after the barrier (no LDS handoff, no extra barrier).
// ---------------------------------------------------------------------------
__global__ __launch_bounds__(1024, 2) void fused_rows(
    const float* __restrict__ z, const bf16* __restrict__ W1p,
    const bf16* __restrict__ W2p, const bf16* __restrict__ W3p,
    const bf16* __restrict__ Pp, const float* __restrict__ b1eff,
    const float* __restrict__ b2,
    float* __restrict__ outV, float* __restrict__ outTr)
{
    __shared__ alignas(16) char smem[88064];
    bf16* zt   = (bf16*)smem;                 // [32][64]  swizzled (4 KB)
    bf16* h1   = (bf16*)(smem + 4096);        // [32][512] swizzled (32 KB)
    bf16* at   = (bf16*)(smem + 36864);       // [32][512] swizzled (32 KB)
    bf16* h2   = (bf16*)(smem + 69632);       // [32][256] swizzled (16 KB)
    float* trp = (float*)(smem + 86016);      // [8][32]            (1 KB)
    float* vp  = (float*)smem;                // [8][32][68] pad, overlays zt+h1+at

    const int tid  = threadIdx.x;
    const int wid  = tid >> 6;                // 0..15
    const int lane = tid & 63;
    const int r    = lane & 15;
    const int kq   = lane >> 4;
    const int rx   = r & 7;
    const int laneE = lane * 8;
    const int rt   = blockIdx.x >> 1;
    const int ch   = blockIdx.x & 1;
    const int bm   = rt * 32;
    const int stream = wid >> 3;              // 0: W2/h1, 1: Pp/at
    const int sw   = wid & 7;                 // 32-col strip within half

    // ---- preload biases (float4 per 4 consecutive cols) BEFORE asm loads ----
    float4 b1v0 = *(const float4*)(b1eff + wid * 32 + kq * 4);
    float4 b1v1 = *(const float4*)(b1eff + wid * 32 + 16 + kq * 4);
    float4 b2v0 = *(const float4*)(b2 + ch * 256 + sw * 32 + kq * 4);
    float4 b2v1 = *(const float4*)(b2 + ch * 256 + sw * 32 + 16 + kq * 4);
    asm volatile("" :: "v"(b1v0.x), "v"(b1v0.y), "v"(b1v0.z), "v"(b1v0.w),
                       "v"(b1v1.x), "v"(b1v1.y), "v"(b1v1.z), "v"(b1v1.w),
                       "v"(b2v0.x), "v"(b2v0.y), "v"(b2v0.z), "v"(b2v0.w),
                       "v"(b2v1.x), "v"(b2v1.y), "v"(b2v1.z), "v"(b2v1.w));
    float b1a[2][4] = {{b1v0.x, b1v0.y, b1v0.z, b1v0.w},
                       {b1v1.x, b1v1.y, b1v1.z, b1v1.w}};
    float b2a[2][4] = {{b2v0.x, b2v0.y, b2v0.z, b2v0.w},
                       {b2v1.x, b2v1.y, b2v1.z, b2v1.w}};

    // ---- stage z: 32x64 f32 -> bf16 swizzled, b64 packed (4 cols/thread) ----
    if (tid < 512) {
        int i = tid * 4;
        int row = i >> 6, col = i & 63;
        float4 v = *(const float4*)(z + (size_t)(bm + row) * DD + col);
        st_swz64(zt, row, col, 64, v.x, v.y, v.z, v.w);
    }

    // ---- L1 prefetch: wave strip = 32 cols, 2 entries (K=64) ----
    short8 q0, q1, q2, q3, p0, p1;
    const bf16* Wb1 = W1p + (size_t)wid * 2048 + laneE;
    GLD2(q0, q1, Wb1);
    GLD2(p0, p1, Wb1 + 1024);
    LGKMBAR();    // zt visible; L1 weight loads stay in flight

    // ---- L1 (swapped): acc1[g][f] = W1frag[f] x zfrag[g] ----
    f32x4 acc1[2][2] = {};    // [g=rowgroup][f=colfrag]
    WAITV(2);
#pragma unroll
    for (int g = 0; g < 2; ++g) {
        short8 av = *(const short8*)(zt + (g * 16 + r) * 64 + ((kq ^ rx) << 3));
        acc1[g][0] = __builtin_amdgcn_mfma_f32_16x16x32_bf16(q0, av, acc1[g][0], 0, 0, 0);
        acc1[g][1] = __builtin_amdgcn_mfma_f32_16x16x32_bf16(q1, av, acc1[g][1], 0, 0, 0);
    }
    WAITV(0);
#pragma unroll
    for (int g = 0; g < 2; ++g) {
        short8 av = *(const short8*)(zt + (g * 16 + r) * 64 + (((4 + kq) ^ rx) << 3));
        acc1[g][0] = __builtin_amdgcn_mfma_f32_16x16x32_bf16(p0, av, acc1[g][0], 0, 0, 0);
        acc1[g][1] = __builtin_amdgcn_mfma_f32_16x16x32_bf16(p1, av, acc1[g][1], 0, 0, 0);
    }
    // stream-loop ring prologue: 3 steps x 2 frags = 6 loads in flight
    short8 rb0[4], rb1[4];
    const bf16* Wstr = (stream ? Pp : W2p)
                     + (size_t)(ch * 16 + sw * 2) * 8192 + laneE;
    GLD1(rb0[0], Wstr);        GLD1(rb1[0], Wstr + 8192);
    GLD1(rb0[1], Wstr + 512);  GLD1(rb1[1], Wstr + 8704);
    GLD1(rb0[2], Wstr + 1024); GLD1(rb1[2], Wstr + 9216);
    // L1 epilogue: lane owns (row=g*16+r, cols wid*32+f*16+kq*4 ..+3) -> b64
#pragma unroll
    for (int g = 0; g < 2; ++g)
#pragma unroll
        for (int f = 0; f < 2; ++f) {
            float hv[4], avv[4];
#pragma unroll
            for (int v = 0; v < 4; ++v) {
                hv[v]  = tanh_fast(acc1[g][f][v] + b1a[f][v]);
                avv[v] = fmaf(-hv[v], hv[v], 1.0f);
            }
            int rowq = g * 16 + r;
            int colq = wid * 32 + f * 16 + kq * 4;
            st_swz64(h1, rowq, colq, 512, hv[0], hv[1], hv[2], hv[3]);
            st_swz64(at, rowq, colq, 512, avv[0], avv[1], avv[2], avv[3]);
        }
    LGKMBAR();    // h1/at visible; ring loads stay in flight

    // ---- stream loop: wave = 32 cols x 32 rows of ONE stream ----
    // per step: 2 A ds_reads (g=0,1) + 2 B GLD1s + 4 MFMA
    const bf16* Ab = stream ? at : h1;
    f32x4 acc[2][2] = {};    // [g][f]
#pragma unroll
    for (int s = 0; s < 16; ++s) {
        int co = (((s * 4 + kq) ^ rx) << 3);
        short8 a0 = *(const short8*)(Ab + r * 512 + co);
        short8 a1 = *(const short8*)(Ab + (16 + r) * 512 + co);
        if (s + 3 < 16) {
            GLD1(rb0[(s + 3) & 3], Wstr + (s + 3) * 512);
            GLD1(rb1[(s + 3) & 3], Wstr + 8192 + (s + 3) * 512);
            WAITV(6);
        } else if (s + 2 < 16) { WAITV(4); }
        else if (s + 1 < 16)   { WAITV(2); }
        else                   { WAITV(0); }
        acc[0][0] = __builtin_amdgcn_mfma_f32_16x16x32_bf16(rb0[s & 3], a0, acc[0][0], 0, 0, 0);
        acc[0][1] = __builtin_amdgcn_mfma_f32_16x16x32_bf16(rb1[s & 3], a0, acc[0][1], 0, 0, 0);
        acc[1][0] = __builtin_amdgcn_mfma_f32_16x16x32_bf16(rb0[s & 3], a1, acc[1][0], 0, 0, 0);
        acc[1][1] = __builtin_amdgcn_mfma_f32_16x16x32_bf16(rb1[s & 3], a1, acc[1][1], 0, 0, 0);
    }
    // W2-waves: write h2 (b64 packed). All waves: L3 prefetch.
    if (stream == 0) {
#pragma unroll
        for (int g = 0; g < 2; ++g)
#pragma unroll
            for (int f = 0; f < 2; ++f) {
                float hv[4];
#pragma unroll
                for (int v = 0; v < 4; ++v)
                    hv[v] = tanh_fast(acc[g][f][v] + b2a[f][v]);
                st_swz64(h2, g * 16 + r, sw * 32 + f * 16 + kq * 4, 256,
                         hv[0], hv[1], hv[2], hv[3]);
            }
    }
    {
        const int kw = wid & 7;
        const bf16* Wb3 = W3p + (size_t)(ch * 8 + kw) * 2048 + laneE;
        GLD4(q0, q1, q2, q3, Wb3);
    }
    LGKMBAR();    // h2 visible; loop reads of h1/at done

    // ---- E-waves: trace, bsq recomputed from bf16 h2 tile ----
    if (stream == 1) {
#pragma unroll
        for (int g = 0; g < 2; ++g) {
            float p = 0.f;
            int rowq = g * 16 + r;
#pragma unroll
            for (int f = 0; f < 2; ++f) {
                int colq = sw * 32 + f * 16 + kq * 4;
                int e = rowq * 256 + ((((colq >> 3) ^ rx)) << 3) + (colq & 7);
                ushort4 hq = *(const ushort4*)(h2 + e);
                float h0 = __uint_as_float((unsigned)hq.x << 16);
                float h1f = __uint_as_float((unsigned)hq.y << 16);
                float h2f = __uint_as_float((unsigned)hq.z << 16);
                float h3 = __uint_as_float((unsigned)hq.w << 16);
                p += acc[g][f][0] * fmaf(-h0, h0, 1.0f)
                   + acc[g][f][1] * fmaf(-h1f, h1f, 1.0f)
                   + acc[g][f][2] * fmaf(-h2f, h2f, 1.0f)
                   + acc[g][f][3] * fmaf(-h3, h3, 1.0f);
            }
            p += __shfl_xor(p, 16);
            p += __shfl_xor(p, 32);
            if (lane < 16) trp[sw * 32 + g * 16 + lane] = p;
        }
    }

    // ---- L3 (swapped): v-partial = W3frag x h2frag; float4 vp stores ----
    {
        const int kw = wid & 7, rp = wid >> 3;
        f32x4 c0 = {}, c1 = {}, c2 = {}, c3 = {};
        short8 av = *(const short8*)(h2 + (rp * 16 + r) * 256 + (((kw * 4 + kq) ^ rx) << 3));
        WAITV(0);
        c0 = __builtin_amdgcn_mfma_f32_16x16x32_bf16(q0, av, c0, 0, 0, 0);
        c1 = __builtin_amdgcn_mfma_f32_16x16x32_bf16(q1, av, c1, 0, 0, 0);
        c2 = __builtin_amdgcn_mfma_f32_16x16x32_bf16(q2, av, c2, 0, 0, 0);
        c3 = __builtin_amdgcn_mfma_f32_16x16x32_bf16(q3, av, c3, 0, 0, 0);
        int base = kw * 2176 + (rp * 16 + r) * 68 + kq * 4;
        *(f32x4*)(vp + base)      = c0;
        *(f32x4*)(vp + base + 16) = c1;
        *(f32x4*)(vp + base + 32) = c2;
        *(f32x4*)(vp + base + 48) = c3;
    }
    LGKMBAR();

    // ---- final: reduce 8 k-chunk partials; atomicAdd v and trace ----
#pragma unroll
    for (int it = 0; it < 2; ++it) {
        int i = it * 1024 + tid;
        int row = i >> 6, col = i & 63;
        float s = 0.f;
#pragma unroll
        for (int kw = 0; kw < 8; ++kw) s += vp[kw * 2176 + row * 68 + col];
        atomicAdd(outV + (size_t)(bm + row) * DD + col, s);
    }
    if (tid < 32) {
        float s = 0.f;
#pragma unroll
        for (int w = 0; w < 8; ++w) s += trp[w * 32 + tid];
        atomicAdd(outTr + bm + tid, -s);
    }
}

extern "C" void kernel_launch(void* const* d_in, const int* in_sizes, int n_in,
                              void* d_out, int out_size, void* d_ws, size_t ws_size,
                              hipStream_t stream)
{
    const float* z  = (const float*)d_in[0];
    const float* t  = (const float*)d_in[2];
    const float* W1 = (const float*)d_in[3];
    const float* b1 = (const float*)d_in[4];
    const float* W2 = (const float*)d_in[5];
    const float* b2 = (const float*)d_in[6];
    const float* W3 = (const float*)d_in[7];
    const float* b3 = (const float*)d_in[8];
    float* out = (float*)d_out;                 // v [4096*64] then dlogp [4096]
    float* out_tr = out + (size_t)BB * DD;

    char* w = (char*)d_ws;
    auto alloc = [&](size_t bytes) {
        char* p = w;
        w += (bytes + 255) & ~(size_t)255;
        return p;
    };
    bf16* W1p   = (bf16*)alloc((size_t)64  * 512 * 2);
    bf16* W2p   = (bf16*)alloc((size_t)512 * 512 * 2);
    bf16* W3p   = (bf16*)alloc((size_t)64  * 512 * 2);
    bf16* Pp    = (bf16*)alloc((size_t)512 * 512 * 2);
    float* b1eff = (float*)alloc((size_t)HH * 4);

    // prep: packs + P (512-block parallel) + b1eff + output init
    prep_kernel<<<933, 256, 0, stream>>>(t, W1, b1, W2, W3, b3,
                                         W1p, W2p, W3p, Pp, b1eff, out);
    fused_rows<<<128 * 2, 1024, 0, stream>>>(z, W1p, W2p, W3p, Pp,
                                             b1eff, b2, out, out_tr);
}